// Round 3
// baseline (16679.483 us; speedup 1.0000x reference)
//
#include <hip/hip_runtime.h>
#include <stdint.h>

#define TT 2048
#define BB 64
#define HH 256

// ws float-word layout
#define WIHT_OFF 0          // W_ih^T : 256 tokens x 1024 gate-rows
#define BIAS_OFF 262144     // b_ih + b_hh : 1024
#define HBUF_OFF 263168     // packed h exchange: u64[2][64][256] = 65536 floats
#define XMAP_OFF 328704     // 256 u32: per-WG published XCC id (0x100 | id)
#define WS_TOT   328960

#define LOGITS   33554432   // 64*2048*256

// ---------------- K1: prep (transpose W_ih, fuse biases, zero exch+xmap) ------
__global__ __launch_bounds__(256, 1) void k_prep(const float* __restrict__ W_ih,
                                                 const float* __restrict__ b_ih,
                                                 const float* __restrict__ b_hh,
                                                 float* ws_f) {
    int idx = blockIdx.x * 256 + threadIdx.x;
    if (idx < 262144) {
        int v = idx >> 10, r = idx & 1023;
        ws_f[WIHT_OFF + idx] = W_ih[r * 256 + v];
    } else if (idx < 263168) {
        int r = idx - 262144;
        ws_f[idx] = b_ih[r] + b_hh[r];
    } else if (idx < WS_TOT) {
        ws_f[idx] = 0.0f;   // exchange slots (epoch=0,val=0) + xcc map = 0
    }
}

// fast activations (no ocml branches); __expf -> v_exp_f32
__device__ __forceinline__ float sigm_f(float x) { return 1.0f / (1.0f + __expf(-x)); }
__device__ __forceinline__ float tanh_f(float x) {
    float e = __expf(2.0f * x);
    return 1.0f - 2.0f / (e + 1.0f);   // +-inf-safe: -> 1 / -1
}

// paired fast-path read: both batches' slots in ONE L2 round trip.
__device__ __forceinline__ void ld_l2x2(const unsigned long long* p0,
                                        const unsigned long long* p1,
                                        unsigned long long& v0,
                                        unsigned long long& v1) {
    asm volatile("global_load_dwordx2 %0, %2, off sc0\n\t"
                 "global_load_dwordx2 %1, %3, off sc0\n\t"
                 "s_waitcnt vmcnt(0)"
                 : "=&v"(v0), "=&v"(v1) : "v"(p0), "v"(p1) : "memory");
}
// fast-path store: plain sc0 store lands DIRTY in the local XCD L2.
__device__ __forceinline__ void st_l2(unsigned long long* p, unsigned long long v) {
    asm volatile("global_store_dwordx2 %0, %1, off sc0" :: "v"(p), "v"(v) : "memory");
}

// LDS-only pre-barrier drain (NO vmcnt: exchange stores are epoch-validated,
// gathers land in private VGPRs — neither needs barrier visibility).
__device__ __forceinline__ void bar_lds() {
    asm volatile("s_waitcnt lgkmcnt(0)" ::: "memory");
    __builtin_amdgcn_sched_barrier(0);
    __builtin_amdgcn_s_barrier();
    __builtin_amdgcn_sched_barrier(0);
}

// ---------------- K2: persistent LSTM recurrence, 2 batches per WG ------------
// 128 WGs x 256 threads. WG (P,q) owns hidden units [q*64,q*64+64) of batches
// b0=P and b1=P+32 (weights shared -> w4 loaded once). Two independent
// recurrence chains interleave in one instruction stream: latency segments
// (poll round trip, barriers, LDS latency) are paid once per pair, compute
// fills the idle pipes. Exchange protocol identical to round 2 (packed
// epoch|value, dual sc0+agent store, XCC handshake, sticky fallback).
__global__ __launch_bounds__(256, 1) void k_lstm(const int* __restrict__ x,
                                                 const float* __restrict__ W_hh,
                                                 const float* __restrict__ wsro,
                                                 unsigned long long* __restrict__ hbuf,
                                                 unsigned* __restrict__ xmap,
                                                 float* __restrict__ out) {
    const int tid = threadIdx.x;
    const int bid = blockIdx.x;
    const int xcd = bid & 7;
    const int g5  = bid >> 3;           // 0..15
    const int q   = g5 & 3;
    const int pg  = g5 >> 2;            // 0..3
    const int b0  = xcd + 8 * pg;       // pair group P in [0,32)
    const int b1  = b0 + 32;
    const int u  = tid & 63;
    const int w  = tid >> 6;            // wave id = quarter it polls; gate id
    const int j  = q * 64 + u;
    const int r  = w * 256 + j;         // gate row in [0,1024)

    __shared__ alignas(16) float hin[2][2][192];  // [parity][pair][rotated slot]
    __shared__ alignas(16) float hloc[4][2][64];  // [wave][pair][u] private copies
    __shared__ float gbuf[2][2][256];             // [parity][pair][gate*64+u]
    __shared__ int xs[4];

    // ---- one-time: W_hh row r -> regs, column-rotated (own quarter last) ----
    float4 w4[64];
#pragma unroll
    for (int i = 0; i < 64; ++i) {
        int cb = (i < 48) ? ((q + 1 + (i >> 4)) & 3) : q;
        int wi = (i < 48) ? (i & 15) : (i - 48);
        w4[i] = *(const float4*)(W_hh + (size_t)r * 256 + cb * 64 + wi * 4);
    }
    const float bias_r = wsro[BIAS_OFF + r];
    const int* xrow0 = x + b0 * TT;
    const int* xrow1 = x + b1 * TT;
    const bool ownw = (w == q);
    const int rb = (w - q + 3) & 3;     // rotated hin slot for polled quarter

    // ---- one-time: XCC handshake (ground truth; failure -> slow mode) ----
    int myxcc = 0;
    asm volatile("s_getreg_b32 %0, hwreg(HW_REG_XCC_ID)" : "=s"(myxcc));
    if (tid == 0)
        __hip_atomic_store(&xmap[bid], 0x100u | (unsigned)myxcc,
                           __ATOMIC_RELAXED, __HIP_MEMORY_SCOPE_AGENT);
    if (tid < 4) {
        int pb = (bid & 7) + 8 * ((pg << 2) + tid);   // the 4 WGs of this pair
        unsigned v; int g = 0;
        do {
            v = __hip_atomic_load(&xmap[pb], __ATOMIC_RELAXED, __HIP_MEMORY_SCOPE_AGENT);
        } while (!(v & 0x100u) && ++g < (1 << 20));
        xs[tid] = (v & 0x100u) ? (int)(v & 0xffu) : -1 - tid;  // timeout -> mismatch
    }
    hloc[w][0][u] = 0.0f;               // h(0) = 0, every wave's private copies
    hloc[w][1][u] = 0.0f;
    float c0 = 0.0f, c1 = 0.0f;         // redundant per wave, identical values
    float h0 = 0.0f, h1 = 0.0f;
    __syncthreads();
    bool fastm = (xs[0] == xs[1]) & (xs[1] == xs[2]) & (xs[2] == xs[3]);

    // prologue prefetch: tokens for t=0 and t=1; gather for t=0
    float xw0 = wsro[WIHT_OFF + xrow0[0] * 1024 + r] + bias_r;
    float xw1 = wsro[WIHT_OFF + xrow1[0] * 1024 + r] + bias_r;
    int tokn0 = xrow0[1], tokn1 = xrow1[1];

    const float4* hl0 = (const float4*)hloc[w][0];
    const float4* hl1 = (const float4*)hloc[w][1];

    for (int t = 0; t < TT; ++t) {
        const int p = t & 1;

        // own-quarter partial dots (private hloc: same-wave RAW, no barrier)
        float a00 = 0.f, a01 = 0.f, a02 = 0.f, a03 = 0.f;
        float a10 = 0.f, a11 = 0.f, a12 = 0.f, a13 = 0.f;
#pragma unroll
        for (int i = 0; i < 16; ++i) {
            float4 hh = hl0[i];
            a00 += w4[48 + i].x * hh.x;
            a01 += w4[48 + i].y * hh.y;
            a02 += w4[48 + i].z * hh.z;
            a03 += w4[48 + i].w * hh.w;
        }
#pragma unroll
        for (int i = 0; i < 16; ++i) {
            float4 hh = hl1[i];
            a10 += w4[48 + i].x * hh.x;
            a11 += w4[48 + i].y * hh.y;
            a12 += w4[48 + i].z * hh.z;
            a13 += w4[48 + i].w * hh.w;
        }

        // poll both batches' remote quarter in ONE round trip per spin.
        // Pollers have no outstanding VMEM here (stores are ownw-only,
        // gathers issue after the barrier) -> vmcnt(0) waits only the poll.
        if (!ownw) {
            const unsigned long long* s0 =
                hbuf + (size_t)p * (BB * HH) + b0 * HH + tid;
            const unsigned long long* s1 =
                hbuf + (size_t)p * (BB * HH) + b1 * HH + tid;
            const unsigned ut = (unsigned)t;
            unsigned long long v0 = 0, v1 = 0;
            if (fastm) {                 // shared-L2 poll, guarded
                int g = 0;
                do { ld_l2x2(s0, s1, v0, v1); }
                while (((unsigned)(v0 >> 32) != ut || (unsigned)(v1 >> 32) != ut)
                       && ++g < 6000);
                if ((unsigned)(v0 >> 32) != ut || (unsigned)(v1 >> 32) != ut)
                    fastm = false;       // sticky fallback
            }
            if (!fastm) {                // proven device-scope path
                int g = 0;
                do {
                    if ((unsigned)(v0 >> 32) != ut)
                        v0 = __hip_atomic_load(s0, __ATOMIC_RELAXED,
                                               __HIP_MEMORY_SCOPE_AGENT);
                    if ((unsigned)(v1 >> 32) != ut)
                        v1 = __hip_atomic_load(s1, __ATOMIC_RELAXED,
                                               __HIP_MEMORY_SCOPE_AGENT);
                } while (((unsigned)(v0 >> 32) != ut || (unsigned)(v1 >> 32) != ut)
                         && ++g < (1 << 21));
            }
            hin[p][0][rb * 64 + u] = __uint_as_float((unsigned)v0);
            hin[p][1][rb * 64 + u] = __uint_as_float((unsigned)v1);
        }
        bar_lds();                       // bar1: hin[p] ready (lgkm drain only)

        // issue next-step gathers + t+2 tokens now — covered by the FMA block
        float xwn0 = wsro[WIHT_OFF + tokn0 * 1024 + r];
        float xwn1 = wsro[WIHT_OFF + tokn1 * 1024 + r];
        const int tt2 = (t + 2 < TT) ? t + 2 : TT - 1;
        tokn0 = xrow0[tt2];
        tokn1 = xrow1[tt2];

        // remaining 3 quarters, branch-free (rotation did the index mapping)
        const float4* hn0 = (const float4*)hin[p][0];
        const float4* hn1 = (const float4*)hin[p][1];
#pragma unroll
        for (int i = 0; i < 48; ++i) {
            float4 hh = hn0[i];
            a00 += w4[i].x * hh.x;
            a01 += w4[i].y * hh.y;
            a02 += w4[i].z * hh.z;
            a03 += w4[i].w * hh.w;
        }
#pragma unroll
        for (int i = 0; i < 48; ++i) {
            float4 hh = hn1[i];
            a10 += w4[i].x * hh.x;
            a11 += w4[i].y * hh.y;
            a12 += w4[i].z * hh.z;
            a13 += w4[i].w * hh.w;
        }
        float gate0 = xw0 + ((a00 + a01) + (a02 + a03));
        float gate1 = xw1 + ((a10 + a11) + (a12 + a13));
        float act0 = (w == 2) ? tanh_f(gate0) : sigm_f(gate0);  // wave-uniform
        float act1 = (w == 2) ? tanh_f(gate1) : sigm_f(gate1);
        gbuf[p][0][tid] = act0;
        gbuf[p][1][tid] = act1;
        bar_lds();                       // bar2: gbuf[p] ready

        // gate combine: redundant on all 4 waves (stride-1, conflict-free)
        float i0 = gbuf[p][0][u],        f0 = gbuf[p][0][64 + u];
        float g0 = gbuf[p][0][128 + u],  o0 = gbuf[p][0][192 + u];
        float i1 = gbuf[p][1][u],        f1 = gbuf[p][1][64 + u];
        float g1 = gbuf[p][1][128 + u],  o1 = gbuf[p][1][192 + u];
        c0 = f0 * c0 + i0 * g0;
        h0 = o0 * tanh_f(c0);
        c1 = f1 * c1 + i1 * g1;
        h1 = o1 * tanh_f(c1);

        if (ownw) {                      // the non-polling wave produces
            unsigned long long pv0 =
                ((unsigned long long)(unsigned)(t + 1) << 32) |
                (unsigned long long)__float_as_uint(h0);
            unsigned long long pv1 =
                ((unsigned long long)(unsigned)(t + 1) << 32) |
                (unsigned long long)__float_as_uint(h1);
            unsigned long long* d0 =
                hbuf + (size_t)((t + 1) & 1) * (BB * HH) + b0 * HH + j;
            unsigned long long* d1 =
                hbuf + (size_t)((t + 1) & 1) * (BB * HH) + b1 * HH + j;
            if (fastm) { st_l2(d0, pv0); st_l2(d1, pv1); }
            __hip_atomic_store(d0, pv0, __ATOMIC_RELAXED, __HIP_MEMORY_SCOPE_AGENT);
            __hip_atomic_store(d1, pv1, __ATOMIC_RELAXED, __HIP_MEMORY_SCOPE_AGENT);
            out[((size_t)(b0 * TT + t) << 8) + j] = h0;          // h history
            out[((size_t)(b1 * TT + t) << 8) + j] = h1;
        }
        hloc[w][0][u] = h0;              // private copies for next step's A
        hloc[w][1][u] = h1;
        xw0 = xwn0 + bias_r;
        xw1 = xwn1 + bias_r;
    }

    if (ownw) {
        out[LOGITS + b0 * HH + j] = h0;                          // h_n
        out[LOGITS + b1 * HH + j] = h1;
        out[LOGITS + BB * HH + b0 * HH + j] = c0;                // c_n
        out[LOGITS + BB * HH + b1 * HH + j] = c1;
    }
}

// ---------------- K3: FC epilogue, in-place over the logits region ------------
__global__ __launch_bounds__(256, 1) void k_fc(const float* __restrict__ fc_W,
                                               const float* __restrict__ fc_b,
                                               float* out) {
    __shared__ alignas(16) float ht[64][256];
    const int tid = threadIdx.x;
    const size_t base = (size_t)blockIdx.x * 64;
    for (int i = 0; i < 64; ++i)
        ht[i][tid] = out[(base + i) * 256 + tid];

    float4 w4[64];
    const float4* wr = (const float4*)(fc_W + (size_t)tid * 256);
#pragma unroll
    for (int k = 0; k < 64; ++k) w4[k] = wr[k];
    const float bias = fc_b[tid];
    __syncthreads();

    for (int m = 0; m < 64; ++m) {
        const float4* hv = (const float4*)ht[m];
        float a0 = 0.f, a1 = 0.f, a2 = 0.f, a3 = 0.f;
#pragma unroll
        for (int k = 0; k < 64; ++k) {
            float4 hh = hv[k];
            a0 += w4[k].x * hh.x;
            a1 += w4[k].y * hh.y;
            a2 += w4[k].z * hh.z;
            a3 += w4[k].w * hh.w;
        }
        out[(base + m) * 256 + tid] = bias + ((a0 + a1) + (a2 + a3));
    }
}

// ---------------- launch ------------------------------------------------------
extern "C" void kernel_launch(void* const* d_in, const int* in_sizes, int n_in,
                              void* d_out, int out_size, void* d_ws, size_t ws_size,
                              hipStream_t stream) {
    const int*   x    = (const int*)d_in[0];
    const float* W_ih = (const float*)d_in[1];
    const float* W_hh = (const float*)d_in[2];
    const float* b_ih = (const float*)d_in[3];
    const float* b_hh = (const float*)d_in[4];
    const float* fc_W = (const float*)d_in[5];
    const float* fc_b = (const float*)d_in[6];
    float* out  = (float*)d_out;
    float* ws_f = (float*)d_ws;
    unsigned long long* hbuf = (unsigned long long*)(ws_f + HBUF_OFF);
    unsigned* xmap = (unsigned*)(ws_f + XMAP_OFF);

    k_prep<<<(WS_TOT + 255) / 256, 256, 0, stream>>>(W_ih, b_ih, b_hh, ws_f);
    k_lstm<<<128, 256, 0, stream>>>(x, W_hh, ws_f, hbuf, xmap, out);
    k_fc<<<2048, 256, 0, stream>>>(fc_W, fc_b, out);
}

// Round 6
// 7728.091 us; speedup vs baseline: 2.1583x; 2.1583x over previous
//
#include <hip/hip_runtime.h>
#include <stdint.h>

#define TT 2048
#define BB 64
#define HH 256

// ws float-word layout
#define WIHT_OFF 0          // W_ih^T : 256 tokens x 1024 gate-rows
#define BIAS_OFF 262144     // b_ih + b_hh : 1024
#define HBUF_OFF 263168     // packed h exchange: u64[2][64][256] = 65536 floats
#define WS_TOT   328960

#define LOGITS   33554432   // 64*2048*256

// ---------------- K1: prep (transpose W_ih, fuse biases, zero exch) -----------
__global__ __launch_bounds__(256, 1) void k_prep(const float* __restrict__ W_ih,
                                                 const float* __restrict__ b_ih,
                                                 const float* __restrict__ b_hh,
                                                 float* ws_f) {
    int idx = blockIdx.x * 256 + threadIdx.x;
    if (idx < 262144) {
        int v = idx >> 10, r = idx & 1023;
        ws_f[WIHT_OFF + idx] = W_ih[r * 256 + v];
    } else if (idx < 263168) {
        int r = idx - 262144;
        ws_f[idx] = b_ih[r] + b_hh[r];
    } else if (idx < WS_TOT) {
        ws_f[idx] = 0.0f;   // exchange slots (epoch=0, val=0)
    }
}

__device__ __forceinline__ float tanh_f(float x) {
    float e = __expf(2.0f * x);
    return 1.0f - 2.0f / (e + 1.0f);   // +-inf-safe: -> 1 / -1
}

// LDS-only pre-barrier drain (proven in round 3). NO vmcnt: exchange stores
// are epoch-validated by their consumers, x_proj prefetch loads land in
// private VGPRs, history stores are consumed only after kernel end.
// __syncthreads would drain vmcnt(0) and put the MALL store-ack round trip on
// the step loop 2-3x per step (the round-0/2 stall).
__device__ __forceinline__ void bar_lds() {
    asm volatile("s_waitcnt lgkmcnt(0)" ::: "memory");
    __builtin_amdgcn_sched_barrier(0);
    __builtin_amdgcn_s_barrier();
    __builtin_amdgcn_sched_barrier(0);
}

// ---------------- K2: persistent LSTM recurrence ------------------------------
// 256 WGs x 256 threads; WG (b,q) owns hidden units [q*64,q*64+64) of batch b.
// QUAD layout (proven round 1): thread = (unit uj = tid>>2, gate s = tid&3).
// Gate combine = 4 intra-quad __shfl broadcasts (proven round 1); c,h computed
// redundantly per quad (bit-identical inputs -> bit-identical results).
// ONE lgkm-only barrier per step (proven round 3); hin/hloc double-buffered by
// parity. Exchange: agent-scope store/poll ONLY (the proven rounds-0..3 path).
// Spin guards are fail-fast (2^15): a broken protocol produces a fast wrong
// answer, never a container-killing hang.
__global__ __launch_bounds__(256, 1) void k_lstm(const int* __restrict__ x,
                                                 const float* __restrict__ W_hh,
                                                 const float* __restrict__ wsro,
                                                 unsigned long long* __restrict__ hbuf,
                                                 float* __restrict__ out) {
    const int tid = threadIdx.x;
    const int bid = blockIdx.x;
    const int xcd  = bid & 7;
    const int slot = bid >> 3;
    const int b = xcd + 8 * (slot >> 2);
    const int q = slot & 3;
    const int s  = tid & 3;             // gate 0=i 1=f 2=g 3=o
    const int uj = tid >> 2;            // unit within quarter [0,64)
    const int j  = q * 64 + uj;         // global hidden index
    const int r  = s * 256 + j;         // gate row in [0,1024)
    const int u  = tid & 63;            // lane in wave

    __shared__ alignas(16) float hin[2][192];   // remote quarters, rotated, dbuf
    __shared__ alignas(16) float hloc[2][64];   // own quarter's h, dbuf

    // ---- one-time: W_hh row r -> regs, column-rotated (own quarter last) ----
    float4 w4[64];
#pragma unroll
    for (int i = 0; i < 64; ++i) {
        int cb = (i < 48) ? ((q + 1 + (i >> 4)) & 3) : q;
        int wi = (i < 48) ? (i & 15) : (i - 48);
        w4[i] = *(const float4*)(W_hh + (size_t)r * 256 + cb * 64 + wi * 4);
    }
    const float bias_r = wsro[BIAS_OFF + r];
    const int* xrow = x + b * TT;

    // poll role: tids [0,192) poll remote quarter cq=(q+1+pk)&3, element pe;
    // slot pk*64+pe == tid matches the w4[0..48) rotated column order.
    const int pk = tid >> 6;
    const int pe = tid & 63;
    const int cq = (q + 1 + pk) & 3;
    const bool pollme = (tid < 192);

    if (tid < 64) hloc[0][tid] = 0.0f;  // h(0) = 0
    float c_state = 0.0f;               // redundant per quad, identical
    float hval = 0.0f;
    __syncthreads();                    // one-time init barrier (full drain ok)

    // gather pipeline: xw_cur ready for t=0, next token known
    float xw_cur = wsro[WIHT_OFF + xrow[0] * 1024 + r] + bias_r;
    int tok1 = xrow[1];

    for (int t = 0; t < TT; ++t) {
        const int p = t & 1;

        // poll remote quarter of h(t): packed (epoch<<32 | value), agent scope
        if (pollme) {
            const unsigned long long* src =
                hbuf + (size_t)p * (BB * HH) + b * HH + cq * 64 + pe;
            const unsigned ut = (unsigned)t;
            unsigned long long v = 0;
            int g = 0;
            do {
                v = __hip_atomic_load(src, __ATOMIC_RELAXED, __HIP_MEMORY_SCOPE_AGENT);
            } while ((unsigned)(v >> 32) != ut && ++g < (1 << 15));
            hin[p][tid] = __uint_as_float((unsigned)v);
        }
        bar_lds();                      // the ONLY per-step barrier (lgkm only)

        // issue t+1 gather + fetch t+2 token — consumed after NEXT barrier,
        // never drained by bar_lds -> a full step of latency cover
        float xw_next = wsro[WIHT_OFF + tok1 * 1024 + r];
        tok1 = xrow[(t + 2 < TT) ? t + 2 : TT - 1];

        // full dot: own quarter from hloc (w4[48..]), remote from hin (w4[0..48))
        const float4* hl4 = (const float4*)hloc[p];
        const float4* hn4 = (const float4*)hin[p];
        float a0 = 0.f, a1 = 0.f, a2 = 0.f, a3 = 0.f;
#pragma unroll
        for (int i = 0; i < 16; ++i) {
            float4 hh = hl4[i];
            a0 += w4[48 + i].x * hh.x;
            a1 += w4[48 + i].y * hh.y;
            a2 += w4[48 + i].z * hh.z;
            a3 += w4[48 + i].w * hh.w;
        }
#pragma unroll
        for (int i = 0; i < 48; ++i) {
            float4 hh = hn4[i];
            a0 += w4[i].x * hh.x;
            a1 += w4[i].y * hh.y;
            a2 += w4[i].z * hh.z;
            a3 += w4[i].w * hh.w;
        }
        float gate = xw_cur + ((a0 + a1) + (a2 + a3));

        // unified branch-free activation: B=2 -> tanh, B=1 -> sigmoid
        const float B2 = (s == 2) ? 2.0f : 1.0f;
        float ex = __expf(B2 * gate);
        float act = 1.0f - B2 / (ex + 1.0f);

        // quad gather of the 4 gates via __shfl (proven round 1)
        const int qb = u & ~3;
        float ig = __shfl(act, qb + 0);
        float fg = __shfl(act, qb + 1);
        float gg = __shfl(act, qb + 2);
        float og = __shfl(act, qb + 3);
        c_state = fg * c_state + ig * gg;
        hval = og * tanh_f(c_state);

        // publish h(t+1): agent-scope store, critical path first
        const int pn = (t + 1) & 1;
        if (s == 0) {
            unsigned long long pv =
                ((unsigned long long)(unsigned)(t + 1) << 32) |
                (unsigned long long)__float_as_uint(hval);
            __hip_atomic_store(hbuf + (size_t)pn * (BB * HH) + b * HH + j,
                               pv, __ATOMIC_RELAXED, __HIP_MEMORY_SCOPE_AGENT);
            hloc[pn][uj] = hval;        // own-quarter copy for next step
        }
        if (s == 1)                      // h history (fire-and-forget)
            out[((size_t)(b * TT + t) << 8) + j] = hval;

        xw_cur = xw_next + bias_r;
    }

    if (s == 0) {
        out[LOGITS + b * HH + j] = hval;                     // h_n
        out[LOGITS + BB * HH + b * HH + j] = c_state;        // c_n
    }
}

// ---------------- K3: FC epilogue, in-place over the logits region ------------
__global__ __launch_bounds__(256, 1) void k_fc(const float* __restrict__ fc_W,
                                               const float* __restrict__ fc_b,
                                               float* out) {
    __shared__ alignas(16) float ht[64][256];
    const int tid = threadIdx.x;
    const size_t base = (size_t)blockIdx.x * 64;
    for (int i = 0; i < 64; ++i)
        ht[i][tid] = out[(base + i) * 256 + tid];

    float4 w4[64];
    const float4* wr = (const float4*)(fc_W + (size_t)tid * 256);
#pragma unroll
    for (int k = 0; k < 64; ++k) w4[k] = wr[k];
    const float bias = fc_b[tid];
    __syncthreads();

    for (int m = 0; m < 64; ++m) {
        const float4* hv = (const float4*)ht[m];
        float a0 = 0.f, a1 = 0.f, a2 = 0.f, a3 = 0.f;
#pragma unroll
        for (int k = 0; k < 64; ++k) {
            float4 hh = hv[k];
            a0 += w4[k].x * hh.x;
            a1 += w4[k].y * hh.y;
            a2 += w4[k].z * hh.z;
            a3 += w4[k].w * hh.w;
        }
        out[(base + m) * 256 + tid] = bias + ((a0 + a1) + (a2 + a3));
    }
}

// ---------------- launch ------------------------------------------------------
extern "C" void kernel_launch(void* const* d_in, const int* in_sizes, int n_in,
                              void* d_out, int out_size, void* d_ws, size_t ws_size,
                              hipStream_t stream) {
    const int*   x    = (const int*)d_in[0];
    const float* W_ih = (const float*)d_in[1];
    const float* W_hh = (const float*)d_in[2];
    const float* b_ih = (const float*)d_in[3];
    const float* b_hh = (const float*)d_in[4];
    const float* fc_W = (const float*)d_in[5];
    const float* fc_b = (const float*)d_in[6];
    float* out  = (float*)d_out;
    float* ws_f = (float*)d_ws;
    unsigned long long* hbuf = (unsigned long long*)(ws_f + HBUF_OFF);

    k_prep<<<(WS_TOT + 255) / 256, 256, 0, stream>>>(W_ih, b_ih, b_hh, ws_f);
    k_lstm<<<256, 256, 0, stream>>>(x, W_hh, ws_f, hbuf, out);
    k_fc<<<2048, 256, 0, stream>>>(fc_W, fc_b, out);
}

// Round 7
// 5882.389 us; speedup vs baseline: 2.8355x; 1.3138x over previous
//
#include <hip/hip_runtime.h>
#include <stdint.h>

#define TT 2048
#define BB 64
#define HH 256

// ws float-word layout
#define WIHT_OFF 0          // W_ih^T : 256 tokens x 1024 gate-rows
#define BIAS_OFF 262144     // b_ih + b_hh : 1024
#define HBUF_OFF 263168     // packed h exchange: u64[2][64][256] = 65536 floats
#define XMAP_OFF 328704     // 256 u32: per-WG published XCC id (0x100 | id)
#define WS_TOT   328960

#define LOGITS   33554432   // 64*2048*256

// ---------------- K1: prep (transpose W_ih, fuse biases, zero exch+xmap) ------
__global__ __launch_bounds__(256, 1) void k_prep(const float* __restrict__ W_ih,
                                                 const float* __restrict__ b_ih,
                                                 const float* __restrict__ b_hh,
                                                 float* ws_f) {
    int idx = blockIdx.x * 256 + threadIdx.x;
    if (idx < 262144) {
        int v = idx >> 10, r = idx & 1023;
        ws_f[WIHT_OFF + idx] = W_ih[r * 256 + v];
    } else if (idx < 263168) {
        int r = idx - 262144;
        ws_f[idx] = b_ih[r] + b_hh[r];
    } else if (idx < WS_TOT) {
        ws_f[idx] = 0.0f;   // exchange slots (epoch=0,val=0) + xcc map = 0
    }
}

// fast activations (no ocml branches); __expf -> v_exp_f32
__device__ __forceinline__ float sigm_f(float x) { return 1.0f / (1.0f + __expf(-x)); }
__device__ __forceinline__ float tanh_f(float x) {
    float e = __expf(2.0f * x);
    return 1.0f - 2.0f / (e + 1.0f);   // +-inf-safe: -> 1 / -1
}

// fast-path read: bypass L1, served from the (shared, same-XCD) L2.
__device__ __forceinline__ unsigned long long ld_l2(const unsigned long long* p) {
    unsigned long long v;
    asm volatile("global_load_dwordx2 %0, %1, off sc0\n\ts_waitcnt vmcnt(0)"
                 : "=v"(v) : "v"(p) : "memory");
    return v;
}
// fast-path store: plain sc0 store lands dirty in the local XCD L2.
__device__ __forceinline__ void st_l2(unsigned long long* p, unsigned long long v) {
    asm volatile("global_store_dwordx2 %0, %1, off sc0" :: "v"(p), "v"(v) : "memory");
}

// LDS-only pre-barrier drain (HW-proven rounds 3/6). NO vmcnt: exchange stores
// are epoch-validated by their consumers, x_proj gathers land in private VGPRs,
// history stores have no in-kernel consumer. __syncthreads would emit
// s_waitcnt vmcnt(0) before s_barrier, putting the agent-store MALL ack
// (~800 cy) on the serial chain TWICE per step — the round-2 residual stall.
__device__ __forceinline__ void bar_lds() {
    asm volatile("s_waitcnt lgkmcnt(0)" ::: "memory");
    __builtin_amdgcn_sched_barrier(0);
    __builtin_amdgcn_s_barrier();
    __builtin_amdgcn_sched_barrier(0);
}

// ---------------- K2: persistent LSTM recurrence ------------------------------
// ROUND-2 STRUCTURE VERBATIM (best measured: 5590 us) with exactly ONE change:
// the two in-loop __syncthreads are now lgkm-only barriers (bar_lds). Wave-gate
// layout; own-quarter dot BEFORE the poll (overlaps exchange latency);
// per-wave private hloc; hin/gbuf double-buffered by parity; dual sc0+agent
// exchange store with sticky fallback (proven round 2).
__global__ __launch_bounds__(256, 1) void k_lstm(const int* __restrict__ x,
                                                 const float* __restrict__ W_hh,
                                                 const float* __restrict__ wsro,
                                                 unsigned long long* __restrict__ hbuf,
                                                 unsigned* __restrict__ xmap,
                                                 float* __restrict__ out) {
    const int tid = threadIdx.x;
    const int bid = blockIdx.x;
    const int xcd  = bid & 7;
    const int slot = bid >> 3;
    const int b = xcd + 8 * (slot >> 2);
    const int q = slot & 3;
    const int u  = tid & 63;
    const int w  = tid >> 6;            // wave id = quarter it polls; gate id
    const int j  = q * 64 + u;
    const int r  = w * 256 + j;         // gate row in [0,1024)

    __shared__ alignas(16) float hin[2][192];   // remote quarters, rotated, dbuf
    __shared__ alignas(16) float hloc[4][64];   // PER-WAVE private copy of own h
    __shared__ float gbuf[2][256];              // gate exchange, dbuf
    __shared__ int xs[4];

    // ---- one-time: W_hh row r -> regs, column-rotated (own quarter last) ----
    float4 w4[64];
#pragma unroll
    for (int i = 0; i < 64; ++i) {
        int cb = (i < 48) ? ((q + 1 + (i >> 4)) & 3) : q;
        int wi = (i < 48) ? (i & 15) : (i - 48);
        w4[i] = *(const float4*)(W_hh + (size_t)r * 256 + cb * 64 + wi * 4);
    }
    const float bias_r = wsro[BIAS_OFF + r];
    const int* xrow = x + b * TT;
    const bool ownw = (w == q);
    const int rb = (w - q + 3) & 3;     // rotated hin slot for polled quarter

    // ---- one-time: XCC handshake (ground truth; failure -> slow mode) ----
    int myxcc = 0;
    asm volatile("s_getreg_b32 %0, hwreg(HW_REG_XCC_ID)" : "=s"(myxcc));
    if (tid == 0)
        __hip_atomic_store(&xmap[bid], 0x100u | (unsigned)myxcc,
                           __ATOMIC_RELAXED, __HIP_MEMORY_SCOPE_AGENT);
    if (tid < 4) {
        int pb = (b & 7) + 8 * ((b >> 3) * 4 + tid);
        unsigned v; int g = 0;
        do {
            v = __hip_atomic_load(&xmap[pb], __ATOMIC_RELAXED, __HIP_MEMORY_SCOPE_AGENT);
        } while (!(v & 0x100u) && ++g < (1 << 20));
        xs[tid] = (v & 0x100u) ? (int)(v & 0xffu) : -1 - tid;  // timeout -> mismatch
    }
    hloc[w][u] = 0.0f;                  // h(0) = 0, every wave's private copy
    float c_state = 0.0f;               // redundant per wave, identical values
    float hval = 0.0f;
    __syncthreads();                    // one-time init barrier (full drain ok)
    bool fastm = (xs[0] == xs[1]) & (xs[1] == xs[2]) & (xs[2] == xs[3]);

    const float4* hl4 = (const float4*)hloc[w];

    // prefetch x_proj for t=0 (coalesced: 256B per wave)
    float xw_cur = wsro[WIHT_OFF + xrow[0] * 1024 + r] + bias_r;

    for (int t = 0; t < TT; ++t) {
        const int p = t & 1;
        // issue next step's gather NOW — a full step of latency cover
        const int tn = (t + 1 < TT) ? t + 1 : t;
        const float xw_next_raw = wsro[WIHT_OFF + xrow[tn] * 1024 + r];

        // own-quarter partial dot from the private hloc copy (same-wave RAW,
        // no barrier needed) — hides under the exchange latency
        float a0 = 0.f, a1 = 0.f, a2 = 0.f, a3 = 0.f;
#pragma unroll
        for (int i = 0; i < 16; ++i) {
            float4 hh = hl4[i];
            a0 += w4[48 + i].x * hh.x;
            a1 += w4[48 + i].y * hh.y;
            a2 += w4[48 + i].z * hh.z;
            a3 += w4[48 + i].w * hh.w;
        }

        // poll remote quarter (packed epoch|value), write rotated slot
        if (!ownw) {
            const unsigned long long* src = hbuf + (size_t)p * (BB * HH) + b * HH + tid;
            const unsigned ut = (unsigned)t;
            unsigned long long v = 0;
            if (fastm) {                 // shared-L2 poll, guarded
                int g = 0;
                do { v = ld_l2(src); } while ((unsigned)(v >> 32) != ut && ++g < 6000);
                if ((unsigned)(v >> 32) != ut) fastm = false;  // sticky fallback
            }
            if (!fastm) {                // proven device-scope path
                int g = 0;
                do {
                    v = __hip_atomic_load(src, __ATOMIC_RELAXED, __HIP_MEMORY_SCOPE_AGENT);
                } while ((unsigned)(v >> 32) != ut && ++g < (1 << 21));
            }
            hin[p][rb * 64 + u] = __uint_as_float((unsigned)v);
        }
        bar_lds();                       // bar1: hin[p] ready (lgkm-only drain)

        // remaining 3 quarters, branch-free (rotation did the index mapping)
        const float4* hn4 = (const float4*)hin[p];
#pragma unroll
        for (int i = 0; i < 48; ++i) {
            float4 hh = hn4[i];
            a0 += w4[i].x * hh.x;
            a1 += w4[i].y * hh.y;
            a2 += w4[i].z * hh.z;
            a3 += w4[i].w * hh.w;
        }
        float gate = xw_cur + ((a0 + a1) + (a2 + a3));
        float act = (w == 2) ? tanh_f(gate) : sigm_f(gate);  // wave-uniform
        gbuf[p][tid] = act;
        bar_lds();                       // bar2: gbuf[p] ready (lgkm-only drain)

        // gate combine: redundant on all 4 waves (stride-1, conflict-free)
        float ig = gbuf[p][u],       fg = gbuf[p][64 + u];
        float gg = gbuf[p][128 + u], og = gbuf[p][192 + u];
        c_state = fg * c_state + ig * gg;
        hval = og * tanh_f(c_state);

        if (ownw) {                      // the non-polling wave produces
            unsigned long long pv =
                ((unsigned long long)(unsigned)(t + 1) << 32) |
                (unsigned long long)__float_as_uint(hval);
            unsigned long long* dst =
                hbuf + (size_t)((t + 1) & 1) * (BB * HH) + b * HH + j;
            if (fastm) st_l2(dst, pv);   // critical-path L2-resident store
            __hip_atomic_store(dst, pv, __ATOMIC_RELAXED, __HIP_MEMORY_SCOPE_AGENT);
            out[((size_t)(b * TT + t) << 8) + j] = hval;     // h history
        }
        hloc[w][u] = hval;               // private copy for next step's A
        xw_cur = xw_next_raw + bias_r;
    }

    if (ownw) {
        out[LOGITS + b * HH + j] = hval;                     // h_n
        out[LOGITS + BB * HH + b * HH + j] = c_state;        // c_n
    }
}

// ---------------- K3: FC epilogue, in-place over the logits region ------------
__global__ __launch_bounds__(256, 1) void k_fc(const float* __restrict__ fc_W,
                                               const float* __restrict__ fc_b,
                                               float* out) {
    __shared__ alignas(16) float ht[64][256];
    const int tid = threadIdx.x;
    const size_t base = (size_t)blockIdx.x * 64;
    for (int i = 0; i < 64; ++i)
        ht[i][tid] = out[(base + i) * 256 + tid];

    float4 w4[64];
    const float4* wr = (const float4*)(fc_W + (size_t)tid * 256);
#pragma unroll
    for (int k = 0; k < 64; ++k) w4[k] = wr[k];
    const float bias = fc_b[tid];
    __syncthreads();

    for (int m = 0; m < 64; ++m) {
        const float4* hv = (const float4*)ht[m];
        float a0 = 0.f, a1 = 0.f, a2 = 0.f, a3 = 0.f;
#pragma unroll
        for (int k = 0; k < 64; ++k) {
            float4 hh = hv[k];
            a0 += w4[k].x * hh.x;
            a1 += w4[k].y * hh.y;
            a2 += w4[k].z * hh.z;
            a3 += w4[k].w * hh.w;
        }
        out[(base + m) * 256 + tid] = bias + ((a0 + a1) + (a2 + a3));
    }
}

// ---------------- launch ------------------------------------------------------
extern "C" void kernel_launch(void* const* d_in, const int* in_sizes, int n_in,
                              void* d_out, int out_size, void* d_ws, size_t ws_size,
                              hipStream_t stream) {
    const int*   x    = (const int*)d_in[0];
    const float* W_ih = (const float*)d_in[1];
    const float* W_hh = (const float*)d_in[2];
    const float* b_ih = (const float*)d_in[3];
    const float* b_hh = (const float*)d_in[4];
    const float* fc_W = (const float*)d_in[5];
    const float* fc_b = (const float*)d_in[6];
    float* out  = (float*)d_out;
    float* ws_f = (float*)d_ws;
    unsigned long long* hbuf = (unsigned long long*)(ws_f + HBUF_OFF);
    unsigned* xmap = (unsigned*)(ws_f + XMAP_OFF);

    k_prep<<<(WS_TOT + 255) / 256, 256, 0, stream>>>(W_ih, b_ih, b_hh, ws_f);
    k_lstm<<<256, 256, 0, stream>>>(x, W_hh, ws_f, hbuf, xmap, out);
    k_fc<<<2048, 256, 0, stream>>>(fc_W, fc_b, out);
}